// Round 1
// baseline (1707.481 us; speedup 1.0000x reference)
//
#include <hip/hip_runtime.h>
#include <hip/hip_bf16.h>
#include <stdint.h>

#define K_DIM 4096
#define N_DIM 4096
#define M_DIM 16384  // 8 * 2048

#define BM 128
#define BN 128
#define BK 64

typedef __attribute__((ext_vector_type(8))) short bf16x8;
typedef __attribute__((ext_vector_type(4))) float f32x4;

__device__ __forceinline__ uint16_t f32_to_bf16_rne(float f) {
    uint32_t u = __builtin_bit_cast(uint32_t, f);
    uint32_t r = (u + 0x7FFFu + ((u >> 16) & 1u)) >> 16;
    return (uint16_t)r;
}

// x (fp32) -> hi bf16 plane + lo bf16 plane (residual). 8 elems/thread.
__global__ __launch_bounds__(256) void convert_x_kernel(
    const float* __restrict__ x,
    uint16_t* __restrict__ xhi,
    uint16_t* __restrict__ xlo) {
    const size_t i = (size_t)blockIdx.x * 256 + threadIdx.x;
    const float4* px = (const float4*)x;
    float4 a = px[2 * i];
    float4 b = px[2 * i + 1];
    float v[8] = {a.x, a.y, a.z, a.w, b.x, b.y, b.z, b.w};
    uint16_t h[8], l[8];
#pragma unroll
    for (int j = 0; j < 8; ++j) {
        float f = v[j];
        uint16_t hb = f32_to_bf16_rne(f);
        float hf = __builtin_bit_cast(float, (uint32_t)hb << 16);
        h[j] = hb;
        l[j] = f32_to_bf16_rne(f - hf);  // exact residual, then RNE
    }
    uint4 hv, lv;
    hv.x = (uint32_t)h[0] | ((uint32_t)h[1] << 16);
    hv.y = (uint32_t)h[2] | ((uint32_t)h[3] << 16);
    hv.z = (uint32_t)h[4] | ((uint32_t)h[5] << 16);
    hv.w = (uint32_t)h[6] | ((uint32_t)h[7] << 16);
    lv.x = (uint32_t)l[0] | ((uint32_t)l[1] << 16);
    lv.y = (uint32_t)l[2] | ((uint32_t)l[3] << 16);
    lv.z = (uint32_t)l[4] | ((uint32_t)l[5] << 16);
    lv.w = (uint32_t)l[6] | ((uint32_t)l[7] << 16);
    ((uint4*)xhi)[i] = hv;
    ((uint4*)xlo)[i] = lv;
}

// W (fp32 ternary) -> bf16 (exact). 8 elems/thread.
__global__ __launch_bounds__(256) void convert_w_kernel(
    const float* __restrict__ w, uint16_t* __restrict__ wb) {
    const size_t i = (size_t)blockIdx.x * 256 + threadIdx.x;
    const float4* pw = (const float4*)w;
    float4 a = pw[2 * i];
    float4 b = pw[2 * i + 1];
    float v[8] = {a.x, a.y, a.z, a.w, b.x, b.y, b.z, b.w};
    uint16_t h[8];
#pragma unroll
    for (int j = 0; j < 8; ++j) h[j] = f32_to_bf16_rne(v[j]);
    uint4 hv;
    hv.x = (uint32_t)h[0] | ((uint32_t)h[1] << 16);
    hv.y = (uint32_t)h[2] | ((uint32_t)h[3] << 16);
    hv.z = (uint32_t)h[4] | ((uint32_t)h[5] << 16);
    hv.w = (uint32_t)h[6] | ((uint32_t)h[7] << 16);
    ((uint4*)wb)[i] = hv;
}

// GEMM: out[M][N] = (Ah + Al)[M][K] . Bw[N][K]^T * scale
// 128x128 tile, BK=64, 4 waves (2x2), each wave 64x64 out.
// Shared-B dual-MFMA: hi and lo planes both multiply the same B fragment.
__global__ __launch_bounds__(256) void gemm_kernel(
    const uint16_t* __restrict__ Ah, const uint16_t* __restrict__ Al,
    const uint16_t* __restrict__ Bw, const float* __restrict__ scale_p,
    float* __restrict__ out) {
    __shared__ __align__(16) uint16_t sAh[BM * BK];
    __shared__ __align__(16) uint16_t sAl[BM * BK];
    __shared__ __align__(16) uint16_t sB[BN * BK];

    const int tid = threadIdx.x;
    const int lane = tid & 63;
    const int wave = tid >> 6;

    // XCD-aware bijective swizzle: nwg = 4096, divisible by 8.
    const int bid = blockIdx.x;
    const int swz = (bid & 7) * (4096 >> 3) + (bid >> 3);
    const int bm = swz >> 5;   // 0..127
    const int bn = swz & 31;   // 0..31

    const uint16_t* gA0 = Ah + (size_t)bm * BM * K_DIM;
    const uint16_t* gA1 = Al + (size_t)bm * BM * K_DIM;
    const uint16_t* gB = Bw + (size_t)bn * BN * K_DIM;

    // staging decomposition: each thread loads one 16B granule per issue
    const int srow = tid >> 3;        // 0..31 (row within 32-row slab)
    const int scol = (tid & 7) << 3;  // elem col offset (0..56 step 8)

    const int wr = wave >> 1, wc = wave & 1;
    const int fr_row = lane & 15;       // fragment row/col within 16
    const int fk = (lane >> 4) << 3;    // k offset per lane group: 0,8,16,24

    f32x4 acc[4][4] = {};

    for (int kt = 0; kt < K_DIM / BK; ++kt) {
        const int kb = kt * BK;
#pragma unroll
        for (int i = 0; i < 4; ++i) {
            const size_t go = (size_t)(i * 32 + srow) * K_DIM + (kb + scol);
            const int lo = i * 4096 + wave * 1024;  // wave-uniform LDS byte base
            __builtin_amdgcn_global_load_lds(
                (const __attribute__((address_space(1))) void*)(gA0 + go),
                (__attribute__((address_space(3))) void*)((char*)sAh + lo), 16, 0, 0);
            __builtin_amdgcn_global_load_lds(
                (const __attribute__((address_space(1))) void*)(gA1 + go),
                (__attribute__((address_space(3))) void*)((char*)sAl + lo), 16, 0, 0);
            __builtin_amdgcn_global_load_lds(
                (const __attribute__((address_space(1))) void*)(gB + go),
                (__attribute__((address_space(3))) void*)((char*)sB + lo), 16, 0, 0);
        }
        __syncthreads();  // drains vmcnt: staged tiles visible

#pragma unroll
        for (int ks = 0; ks < 2; ++ks) {
            bf16x8 ah[4], al[4], bb[4];
            const int co = ks * 32 + fk;
#pragma unroll
            for (int f = 0; f < 4; ++f) {
                const int ar = wr * 64 + f * 16 + fr_row;
                ah[f] = *(const bf16x8*)&sAh[ar * BK + co];
                al[f] = *(const bf16x8*)&sAl[ar * BK + co];
                const int br = wc * 64 + f * 16 + fr_row;
                bb[f] = *(const bf16x8*)&sB[br * BK + co];
            }
#pragma unroll
            for (int i = 0; i < 4; ++i)
#pragma unroll
                for (int j = 0; j < 4; ++j) {
                    acc[i][j] = __builtin_amdgcn_mfma_f32_16x16x32_bf16(
                        ah[i], bb[j], acc[i][j], 0, 0, 0);
                    acc[i][j] = __builtin_amdgcn_mfma_f32_16x16x32_bf16(
                        al[i], bb[j], acc[i][j], 0, 0, 0);
                }
        }
        __syncthreads();  // compute done before next stage overwrites
    }

    // Epilogue: C/D layout col = lane&15, row = 4*(lane>>4) + reg
    const float s = *scale_p;
    const int r0 = bm * BM + wr * 64;
    const int c0 = bn * BN + wc * 64 + (lane & 15);
    const int rsub = (lane >> 4) * 4;
#pragma unroll
    for (int i = 0; i < 4; ++i)
#pragma unroll
        for (int j = 0; j < 4; ++j)
#pragma unroll
            for (int r = 0; r < 4; ++r)
                out[(size_t)(r0 + i * 16 + rsub + r) * N_DIM + (c0 + j * 16)] =
                    acc[i][j][r] * s;
}

extern "C" void kernel_launch(void* const* d_in, const int* in_sizes, int n_in,
                              void* d_out, int out_size, void* d_ws, size_t ws_size,
                              hipStream_t stream) {
    const float* x = (const float*)d_in[0];        // [8,2048,4096]
    const float* qw = (const float*)d_in[1];       // [4096,4096] ternary
    const float* wscale = (const float*)d_in[2];   // scalar
    float* out = (float*)d_out;                    // [8,2048,4096]

    // workspace layout: xhi (128 MiB) | xlo (128 MiB) | wb (32 MiB)
    uint16_t* xhi = (uint16_t*)d_ws;
    uint16_t* xlo = xhi + (size_t)M_DIM * K_DIM;
    uint16_t* wb = xlo + (size_t)M_DIM * K_DIM;

    convert_x_kernel<<<(M_DIM * K_DIM) / 2048, 256, 0, stream>>>(x, xhi, xlo);
    convert_w_kernel<<<(N_DIM * K_DIM) / 2048, 256, 0, stream>>>(qw, wb);

    const int grid = (M_DIM / BM) * (N_DIM / BN);  // 4096
    gemm_kernel<<<grid, 256, 0, stream>>>(xhi, xlo, wb, wscale, out);
}

// Round 2
// 1071.863 us; speedup vs baseline: 1.5930x; 1.5930x over previous
//
#include <hip/hip_runtime.h>
#include <hip/hip_bf16.h>
#include <stdint.h>

#define K_DIM 4096
#define N_DIM 4096
#define M_DIM 16384  // 8 * 2048

#define BM 256
#define BN 256
#define BK 64
#define NT (K_DIM / BK)  // 64 K-tiles

typedef _Float16 f16x8 __attribute__((ext_vector_type(8)));
typedef float f32x4 __attribute__((ext_vector_type(4)));

// ---------------- fp32 -> f16 conversion (8 elems/thread) ----------------
__global__ __launch_bounds__(256) void convert_f16_kernel(
    const float* __restrict__ in, uint16_t* __restrict__ out_) {
    const size_t i = (size_t)blockIdx.x * 256 + threadIdx.x;
    const float4* p = (const float4*)in;
    float4 a = p[2 * i];
    float4 b = p[2 * i + 1];
    float v[8] = {a.x, a.y, a.z, a.w, b.x, b.y, b.z, b.w};
    uint16_t h[8];
#pragma unroll
    for (int j = 0; j < 8; ++j) {
        _Float16 f = (_Float16)v[j];  // RNE v_cvt_f16_f32
        h[j] = __builtin_bit_cast(uint16_t, f);
    }
    uint4 hv;
    hv.x = (uint32_t)h[0] | ((uint32_t)h[1] << 16);
    hv.y = (uint32_t)h[2] | ((uint32_t)h[3] << 16);
    hv.z = (uint32_t)h[4] | ((uint32_t)h[5] << 16);
    hv.w = (uint32_t)h[6] | ((uint32_t)h[7] << 16);
    ((uint4*)out_)[i] = hv;
}

// ---------------- 256x256 tile, BK=64, 8 waves, 4-phase pipelined GEMM ----
// LDS layout per [row][64] f16 tile: 128B rows, 8x 16B slots per row.
// XOR swizzle (T2 / G4): logical slot S of row r lives at LDS slot S^(r&7).
// global_load_lds writes linearly; source column is pre-swizzled (rule 21).

__device__ __forceinline__ void stage_round(const uint16_t* __restrict__ gmat,
                                            uint16_t* lds, int r, int tid,
                                            int kb) {
    const int g = r * 512 + tid;     // granule id (16B)
    const int row = g >> 3;          // tile row
    const int sl = g & 7;            // 16B slot within row
    const uint16_t* src =
        gmat + (size_t)row * K_DIM + kb + ((sl ^ (row & 7)) << 3);
    __builtin_amdgcn_global_load_lds(
        (const __attribute__((address_space(1))) void*)src,
        (__attribute__((address_space(3))) void*)((char*)lds + (size_t)g * 16),
        16, 0, 0);
}

__global__ __launch_bounds__(512, 2) void gemm_kernel(
    const uint16_t* __restrict__ A, const uint16_t* __restrict__ B,
    const float* __restrict__ scale_p, float* __restrict__ out) {
    __shared__ __align__(16) uint16_t sA[2][BM * BK];  // 2 x 32 KiB
    __shared__ __align__(16) uint16_t sB[2][BN * BK];  // 2 x 32 KiB

    const int tid = threadIdx.x;
    const int lane = tid & 63;
    const int wave = tid >> 6;  // 0..7
    const int wr = wave >> 2;   // 0..1  (M half: 128 rows)
    const int wc = wave & 3;    // 0..3  (N quarter: 64 cols)

    // XCD-aware bijective swizzle (nwg = 1024, %8 == 0)
    const int bid = blockIdx.x;
    const int swz = (bid & 7) * 128 + (bid >> 3);
    const int bm = swz >> 4;  // 0..63
    const int bn = swz & 15;  // 0..15

    const uint16_t* gA = A + (size_t)bm * BM * K_DIM;
    const uint16_t* gB = B + (size_t)bn * BN * K_DIM;

    const int fr = lane & 15;  // fragment row within 16
    const int kh = lane >> 4;  // k-group 0..3

    f32x4 acc[8][4] = {};
    const float s = *scale_p;

    // swizzled ds_read address of fragment (row, ks)
    auto frag = [&](const uint16_t* base, int row, int ks) -> f16x8 {
        const int sl = (ks * 4 + kh) ^ (row & 7);
        return *(const f16x8*)((const char*)base + row * 128 + sl * 16);
    };

    // prologue: stage tile 0 into buffer 0
#pragma unroll
    for (int r = 0; r < 4; ++r) stage_round(gA, &sA[0][0], r, tid, 0);
#pragma unroll
    for (int r = 0; r < 4; ++r) stage_round(gB, &sB[0][0], r, tid, 0);

    int c = 0;
    for (int t = 0; t < NT; ++t) {
        const int kb_n = ((t + 1) < NT ? (t + 1) : 0) * BK;  // dummy re-stage on last
        const uint16_t* sa = &sA[c][0];
        const uint16_t* sb = &sB[c][0];
        uint16_t* na = &sA[c ^ 1][0];
        uint16_t* nb = &sB[c ^ 1][0];

        f16x8 bb[4][2], a0[2], a1[2];

#define MFMA16(I0, I1)                                                        \
    asm volatile("s_waitcnt lgkmcnt(0)" ::: "memory");                        \
    __builtin_amdgcn_sched_barrier(0);                                        \
    __builtin_amdgcn_s_setprio(1);                                            \
    _Pragma("unroll") for (int j = 0; j < 4; ++j) {                           \
        acc[I0][j] = __builtin_amdgcn_mfma_f32_16x16x32_f16(a0[0], bb[j][0],  \
                                                            acc[I0][j], 0, 0, 0); \
        acc[I0][j] = __builtin_amdgcn_mfma_f32_16x16x32_f16(a0[1], bb[j][1],  \
                                                            acc[I0][j], 0, 0, 0); \
        acc[I1][j] = __builtin_amdgcn_mfma_f32_16x16x32_f16(a1[0], bb[j][0],  \
                                                            acc[I1][j], 0, 0, 0); \
        acc[I1][j] = __builtin_amdgcn_mfma_f32_16x16x32_f16(a1[1], bb[j][1],  \
                                                            acc[I1][j], 0, 0, 0); \
    }                                                                         \
    __builtin_amdgcn_s_setprio(0);

        // ---- phase 0 ----
        stage_round(gA, na, 0, tid, kb_n);
        stage_round(gA, na, 1, tid, kb_n);
        asm volatile("s_waitcnt vmcnt(2)" ::: "memory");  // tile t fully staged
        __builtin_amdgcn_s_barrier();                     // visible to all waves
        __builtin_amdgcn_sched_barrier(0);
#pragma unroll
        for (int j = 0; j < 4; ++j) {
            bb[j][0] = frag(sb, wc * 64 + j * 16 + fr, 0);
            bb[j][1] = frag(sb, wc * 64 + j * 16 + fr, 1);
        }
        a0[0] = frag(sa, wr * 128 + 0 * 16 + fr, 0);
        a0[1] = frag(sa, wr * 128 + 0 * 16 + fr, 1);
        a1[0] = frag(sa, wr * 128 + 1 * 16 + fr, 0);
        a1[1] = frag(sa, wr * 128 + 1 * 16 + fr, 1);
        MFMA16(0, 1)

        // ---- phase 1 ----
        stage_round(gA, na, 2, tid, kb_n);
        stage_round(gA, na, 3, tid, kb_n);
        a0[0] = frag(sa, wr * 128 + 2 * 16 + fr, 0);
        a0[1] = frag(sa, wr * 128 + 2 * 16 + fr, 1);
        a1[0] = frag(sa, wr * 128 + 3 * 16 + fr, 0);
        a1[1] = frag(sa, wr * 128 + 3 * 16 + fr, 1);
        MFMA16(2, 3)

        // ---- phase 2 ----
        stage_round(gB, nb, 0, tid, kb_n);
        stage_round(gB, nb, 1, tid, kb_n);
        a0[0] = frag(sa, wr * 128 + 4 * 16 + fr, 0);
        a0[1] = frag(sa, wr * 128 + 4 * 16 + fr, 1);
        a1[0] = frag(sa, wr * 128 + 5 * 16 + fr, 0);
        a1[1] = frag(sa, wr * 128 + 5 * 16 + fr, 1);
        MFMA16(4, 5)

        // ---- phase 3 ----
        stage_round(gB, nb, 2, tid, kb_n);
        stage_round(gB, nb, 3, tid, kb_n);
        a0[0] = frag(sa, wr * 128 + 6 * 16 + fr, 0);
        a0[1] = frag(sa, wr * 128 + 6 * 16 + fr, 1);
        a1[0] = frag(sa, wr * 128 + 7 * 16 + fr, 0);
        a1[1] = frag(sa, wr * 128 + 7 * 16 + fr, 1);
        MFMA16(6, 7)

        __builtin_amdgcn_s_barrier();  // all waves done reading buf c
        c ^= 1;
#undef MFMA16
    }

    asm volatile("s_waitcnt vmcnt(0)" ::: "memory");  // drain dummy prefetch

    // Epilogue: C/D layout col = lane&15, row = 4*(lane>>4) + reg
    const int r0 = bm * BM + wr * 128;
    const int c0 = bn * BN + wc * 64 + fr;
    const int rs = kh * 4;
#pragma unroll
    for (int i = 0; i < 8; ++i)
#pragma unroll
        for (int j = 0; j < 4; ++j)
#pragma unroll
            for (int r = 0; r < 4; ++r)
                out[(size_t)(r0 + i * 16 + rs + r) * N_DIM + (c0 + j * 16)] =
                    acc[i][j][r] * s;
}

extern "C" void kernel_launch(void* const* d_in, const int* in_sizes, int n_in,
                              void* d_out, int out_size, void* d_ws, size_t ws_size,
                              hipStream_t stream) {
    const float* x = (const float*)d_in[0];       // [8,2048,4096] fp32
    const float* qw = (const float*)d_in[1];      // [4096,4096] ternary fp32
    const float* wscale = (const float*)d_in[2];  // scalar
    float* out = (float*)d_out;

    // workspace: xf16 (128 MiB) | wf16 (32 MiB)
    uint16_t* xf16 = (uint16_t*)d_ws;
    uint16_t* wf16 = xf16 + (size_t)M_DIM * K_DIM;

    convert_f16_kernel<<<(M_DIM * (size_t)K_DIM) / 2048, 256, 0, stream>>>(x, xf16);
    convert_f16_kernel<<<(N_DIM * (size_t)K_DIM) / 2048, 256, 0, stream>>>(qw, wf16);

    const int grid = (M_DIM / BM) * (N_DIM / BN);  // 1024
    gemm_kernel<<<grid, 512, 0, stream>>>(xf16, wf16, wscale, out);
}

// Round 4
// 987.304 us; speedup vs baseline: 1.7294x; 1.0856x over previous
//
#include <hip/hip_runtime.h>
#include <stdint.h>

#define K_DIM 4096
#define N_DIM 4096
#define M_DIM 16384  // 8 * 2048

#define BM 256
#define BN 256
#define BK 64
#define NT (K_DIM / BK)  // 64 K-tiles

typedef _Float16 f16x8 __attribute__((ext_vector_type(8)));
typedef float f32x4 __attribute__((ext_vector_type(4)));

// ---------------- fp32 -> f16 conversion, grid-stride (G11) ----------------
__global__ __launch_bounds__(256) void convert_f16_kernel(
    const float* __restrict__ in, uint16_t* __restrict__ o, long n8) {
    const long stride = (long)gridDim.x * 256;
    for (long i = (long)blockIdx.x * 256 + threadIdx.x; i < n8; i += stride) {
        float4 a = ((const float4*)in)[2 * i];
        float4 b = ((const float4*)in)[2 * i + 1];
        float v[8] = {a.x, a.y, a.z, a.w, b.x, b.y, b.z, b.w};
        uint16_t h[8];
#pragma unroll
        for (int j = 0; j < 8; ++j) {
            _Float16 f = (_Float16)v[j];  // RNE v_cvt_f16_f32
            h[j] = __builtin_bit_cast(uint16_t, f);
        }
        uint4 hv;
        hv.x = (uint32_t)h[0] | ((uint32_t)h[1] << 16);
        hv.y = (uint32_t)h[2] | ((uint32_t)h[3] << 16);
        hv.z = (uint32_t)h[4] | ((uint32_t)h[5] << 16);
        hv.w = (uint32_t)h[6] | ((uint32_t)h[7] << 16);
        ((uint4*)o)[i] = hv;
    }
}

// ------------- 256x256, BK=64, 8 waves, per-phase-barrier 8-phase GEMM ------
// LDS tile rows are 128B (64 f16). T2 XOR swizzle: 16B slot S of row r lives at
// S^(r&7); global_load_lds writes linearly, source col pre-swizzled (rule 21).
// Schedule per 2-K-tile iteration (tiles 2t->buf0, 2t+1->buf1), per half h:
//   q0: stage A(next)->buf[h^1] | ds_read 8 B-frags + 4 A | bar | MFMA(0,1) | bar
//   q1: stage B(next)->buf[h^1] | ds_read 4 A            | bar | MFMA(2,3) | bar
//   q2:                           ds_read 4 A            | bar | MFMA(4,5) | bar
//   q3:                           ds_read 4 A | vmcnt(0) | bar | MFMA(6,7) | bar
// Ledger: stage into buf[h^1] follows bar2 of its last reader phase; reads of
// buf[h] are covered by the previous half's q3 vmcnt(0)+bar1; lgkmcnt(0)+
// sched_barrier(0) precede every MFMA cluster (rule 18).

__global__ __launch_bounds__(512, 2) void gemm_kernel(
    const uint16_t* __restrict__ A, const uint16_t* __restrict__ B,
    const float* __restrict__ scale_p, float* __restrict__ out) {
    __shared__ __align__(16) uint16_t sA[2][BM * BK];  // 2 x 32 KiB
    __shared__ __align__(16) uint16_t sB[2][BN * BK];  // 2 x 32 KiB

    const int tid = threadIdx.x;
    const int lane = tid & 63;
    const int wave = tid >> 6;  // 0..7
    const int wr = wave >> 2;   // 0..1  (M half: 128 rows)
    const int wc = wave & 3;    // 0..3  (N quarter: 64 cols)

    // XCD-aware bijective swizzle (nwg = 1024, %8 == 0) — T1
    const int bid = blockIdx.x;
    const int swz = (bid & 7) * 128 + (bid >> 3);
    const int bm = swz >> 4;  // 0..63
    const int bn = swz & 15;  // 0..15

    // staging: granule g = r*512+tid; row = r*64 + (tid>>3); slot = tid&7
    const int srow = tid >> 3;
    const int swcol = (((tid & 7) ^ (srow & 7)) << 3);  // pre-swizzled col (elems)
    const uint16_t* gAbase = A + (size_t)(bm * BM + srow) * K_DIM + swcol;
    const uint16_t* gBbase = B + (size_t)(bn * BN + srow) * K_DIM + swcol;
    const int ldst = tid * 16;  // LDS dst byte offset at r=0

#define STAGE(gbase, ldsbuf, kbs)                                             \
    _Pragma("unroll") for (int r = 0; r < 4; ++r)                             \
        __builtin_amdgcn_global_load_lds(                                     \
            (const __attribute__((address_space(1))) void*)((gbase) + (kbs) + \
                                                            (size_t)r * 64 * K_DIM), \
            (__attribute__((address_space(3))) void*)((char*)(ldsbuf) +       \
                                                      r * 8192 + ldst),       \
            16, 0, 0);

    // fragment addressing (read-side swizzle): row&7 == fr&7 for all frag rows
    const int fr = lane & 15;
    const int kh = lane >> 4;
    const int x0 = (kh ^ (fr & 7)) << 4;  // byte slot for ks=0
    const int x1 = x0 ^ 64;               // ks=1
    const int aLane = (wr * 128 + fr) * 128;  // byte row base in A tile
    const int bLane = (wc * 64 + fr) * 128;

    f32x4 acc[8][4] = {};
    const float s = *scale_p;

#define MFMA16(I0, I1)                                                         \
    asm volatile("s_waitcnt lgkmcnt(0)" ::: "memory");                         \
    __builtin_amdgcn_sched_barrier(0);                                         \
    __builtin_amdgcn_s_setprio(1);                                             \
    _Pragma("unroll") for (int j = 0; j < 4; ++j) {                            \
        acc[I0][j] = __builtin_amdgcn_mfma_f32_16x16x32_f16(a0[0], bb[j][0],   \
                                                            acc[I0][j], 0, 0, 0); \
        acc[I0][j] = __builtin_amdgcn_mfma_f32_16x16x32_f16(a0[1], bb[j][1],   \
                                                            acc[I0][j], 0, 0, 0); \
        acc[I1][j] = __builtin_amdgcn_mfma_f32_16x16x32_f16(a1[0], bb[j][0],   \
                                                            acc[I1][j], 0, 0, 0); \
        acc[I1][j] = __builtin_amdgcn_mfma_f32_16x16x32_f16(a1[1], bb[j][1],   \
                                                            acc[I1][j], 0, 0, 0); \
    }                                                                          \
    __builtin_amdgcn_s_setprio(0);

#define AREADS(Q)                                              \
    a0[0] = *(const f16x8*)(pa + (2 * (Q)) * 2048 + x0);       \
    a0[1] = *(const f16x8*)(pa + (2 * (Q)) * 2048 + x1);       \
    a1[0] = *(const f16x8*)(pa + (2 * (Q) + 1) * 2048 + x0);   \
    a1[1] = *(const f16x8*)(pa + (2 * (Q) + 1) * 2048 + x1);

    // prologue: stage tile 0 into buf0, full drain
    STAGE(gAbase, &sA[0][0], 0)
    STAGE(gBbase, &sB[0][0], 0)
    asm volatile("s_waitcnt vmcnt(0)" ::: "memory");
    __builtin_amdgcn_s_barrier();

    for (int t = 0; t < NT / 2; ++t) {
#pragma unroll
        for (int h = 0; h < 2; ++h) {
            const int kt = 2 * t + h;
            const size_t kbs = (size_t)((kt + 1 < NT) ? (kt + 1) : 0) * BK;
            const char* pa = (const char*)&sA[h][0] + aLane;
            const char* pb = (const char*)&sB[h][0] + bLane;
            uint16_t* na = &sA[h ^ 1][0];
            uint16_t* nb = &sB[h ^ 1][0];

            f16x8 bb[4][2], a0[2], a1[2];

            // ---- q0 ----
            STAGE(gAbase, na, kbs)
#pragma unroll
            for (int j = 0; j < 4; ++j) {
                bb[j][0] = *(const f16x8*)(pb + j * 2048 + x0);
                bb[j][1] = *(const f16x8*)(pb + j * 2048 + x1);
            }
            AREADS(0)
            __builtin_amdgcn_s_barrier();
            MFMA16(0, 1)
            __builtin_amdgcn_s_barrier();

            // ---- q1 ----
            STAGE(gBbase, nb, kbs)
            AREADS(1)
            __builtin_amdgcn_s_barrier();
            MFMA16(2, 3)
            __builtin_amdgcn_s_barrier();

            // ---- q2 ----
            AREADS(2)
            __builtin_amdgcn_s_barrier();
            MFMA16(4, 5)
            __builtin_amdgcn_s_barrier();

            // ---- q3 ----
            AREADS(3)
            asm volatile("s_waitcnt vmcnt(0)" ::: "memory");  // next tile landed
            __builtin_amdgcn_s_barrier();
            MFMA16(6, 7)
            __builtin_amdgcn_s_barrier();
        }
    }

    asm volatile("s_waitcnt vmcnt(0)" ::: "memory");  // drain dummy prefetch

    // Epilogue: C/D layout col = lane&15, row = 4*(lane>>4) + reg
    const int r0 = bm * BM + wr * 128;
    const int c0 = bn * BN + wc * 64 + fr;
    const int rs = kh * 4;
#pragma unroll
    for (int i = 0; i < 8; ++i)
#pragma unroll
        for (int j = 0; j < 4; ++j)
#pragma unroll
            for (int r = 0; r < 4; ++r)
                out[(size_t)(r0 + i * 16 + rs + r) * N_DIM + (c0 + j * 16)] =
                    acc[i][j][r] * s;
#undef STAGE
#undef MFMA16
#undef AREADS
}

extern "C" void kernel_launch(void* const* d_in, const int* in_sizes, int n_in,
                              void* d_out, int out_size, void* d_ws, size_t ws_size,
                              hipStream_t stream) {
    const float* x = (const float*)d_in[0];       // [8,2048,4096] fp32
    const float* qw = (const float*)d_in[1];      // [4096,4096] ternary fp32
    const float* wscale = (const float*)d_in[2];  // scalar
    float* out = (float*)d_out;

    // workspace: xf16 (128 MiB) | wf16 (32 MiB)
    uint16_t* xf16 = (uint16_t*)d_ws;
    uint16_t* wf16 = xf16 + (size_t)M_DIM * K_DIM;

    convert_f16_kernel<<<2048, 256, 0, stream>>>(x, xf16,
                                                 (long)M_DIM * K_DIM / 8);
    convert_f16_kernel<<<2048, 256, 0, stream>>>(qw, wf16,
                                                 (long)N_DIM * K_DIM / 8);

    const int grid = (M_DIM / BM) * (N_DIM / BN);  // 1024
    gemm_kernel<<<grid, 512, 0, stream>>>(xf16, wf16, wscale, out);
}